// Round 8
// baseline (149.446 us; speedup 1.0000x reference)
//
#include <hip/hip_runtime.h>
#include <stdint.h>

#define BB 16
#define NN 2048
#define CC 80
#define CONF_THRV 0.5f
#define NMS_THRV 0.5f

// ============ K1: keys + rank + own-anchor classify + scatter + tail-out ===
// Grid (NN/256, BB) = 128 blocks. Keys depend only on obj; each block
// rebuilds the batch's keys from an 8 KB obj read. rank[i] = #{key_j > key_i}
// (unique keys => exact stable argsort(-score)). Invalid anchors skip
// rank/argmax/scatter. NEW: slot i >= nv gets its scan-independent tail
// output row [b,0,...,0] here (full grid) instead of in the 16-block scan.
__global__ __launch_bounds__(256) void k_rank_all(
    const float4* __restrict__ boxes,
    const float* __restrict__ obj,
    const float* __restrict__ logits,
    float4* __restrict__ sxyxy,
    float* __restrict__ sarea,
    float* __restrict__ sobj,
    float* __restrict__ sconf,
    int* __restrict__ scls,
    int* __restrict__ nvalid,
    float* __restrict__ out) {
  __shared__ unsigned long long lk[NN];   // 16 KB
  __shared__ int cnt;
  int b = blockIdx.y;
  int t = threadIdx.x;
  if (t == 0) cnt = 0;
  __syncthreads();
  size_t base = (size_t)b * NN;
  int myv = 0;
  #pragma unroll
  for (int r = 0; r < NN / 256; ++r) {
    int a = t + r * 256;
    float o = obj[base + a];
    bool v = o > CONF_THRV;
    float s = v ? o : -INFINITY;
    unsigned u = __float_as_uint(s);
    u = (u & 0x80000000u) ? ~u : (u | 0x80000000u);
    // descending key: score major, smaller original index first on ties
    lk[a] = ((unsigned long long)u << 32) |
            (unsigned long long)(0xFFFFFFFFu - (unsigned)a);
    myv += v ? 1 : 0;
  }
  atomicAdd(&cnt, myv);
  __syncthreads();
  if (t == 0) nvalid[b] = cnt;            // 8 blocks/batch write same value
  int nv = cnt;

  int i = blockIdx.x * 256 + t;
  // tail output rows are scan-independent: [b, 0,...,0]
  if (i >= nv) {
    float4* op = (float4*)(out + (base + i) * 8);
    op[0] = make_float4((float)b, 0.f, 0.f, 0.f);
    op[1] = make_float4(0.f, 0.f, 0.f, 0.f);
  }

  unsigned long long ki = lk[i];
  // valid <=> obj>0.5 <=> key > (flip(0.5f)<<32 | 0xFFFFFFFF)
  const unsigned long long VK = (0xBF000000ull << 32) | 0xFFFFFFFFull;
  if (ki <= VK) return;                   // slot rank>=nv is never read

  int rank = 0;
  const ulonglong2* lk2 = (const ulonglong2*)lk;
  #pragma unroll 4
  for (int j = 0; j < NN / 2; j += 2) {   // broadcast LDS reads, b128 pairs
    ulonglong2 a2 = lk2[j];
    ulonglong2 c2 = lk2[j + 1];
    rank += (a2.x > ki) + (a2.y > ki) + (c2.x > ki) + (c2.y > ki);
  }

  // class argmax for own (valid) anchor only — ~half the logits traffic
  const float4* lp = (const float4*)(logits + (base + i) * CC);
  float best = -INFINITY;
  int bi = 0;
  #pragma unroll
  for (int q = 0; q < CC / 4; ++q) {
    float4 v4 = lp[q];
    if (v4.x > best) { best = v4.x; bi = 4 * q + 0; }
    if (v4.y > best) { best = v4.y; bi = 4 * q + 1; }
    if (v4.z > best) { best = v4.z; bi = 4 * q + 2; }
    if (v4.w > best) { best = v4.w; bi = 4 * q + 3; }
  }

  float4 bx = boxes[base + i];
  float hw = bx.z / 2.0f, hh = bx.w / 2.0f;
  float x1 = bx.x - hw, y1 = bx.y - hh;
  float x2 = bx.x + hw, y2 = bx.y + hh;
  sxyxy[base + rank] = make_float4(x1, y1, x2, y2);
  sarea[base + rank] = __fmul_rn(x2 - x1 + 1.0f, y2 - y1 + 1.0f);
  sobj[base + rank] = obj[base + i];
  sconf[base + rank] = best;
  scls[base + rank] = bi;
}

// ============ K2: suppression masks, transposed, only live words ===========
// masksT[(b*64 + w)*NN + i] = bits for rows j in [32w,32w+32) suppressed by i.
// Only words w < nwords=ceil(nv/32) stored; all i in [0,2048) written (zeros
// where dead) so the scan's rounded-up chunks OR in zeros harmlessly.
__global__ void k_masks(const float4* __restrict__ sxyxy,
                        const float* __restrict__ sarea,
                        const int* __restrict__ scls,
                        const int* __restrict__ nvalid,
                        uint32_t* __restrict__ masksT) {
  int b = blockIdx.y;
  int pair = blockIdx.x * blockDim.x + threadIdx.x;  // [0, NN*64)
  int i = pair & (NN - 1);
  int w = pair >> 11;
  int nv = nvalid[b];
  int nwords = (nv + 31) >> 5;
  if (w >= nwords) return;              // scan never reads these words
  size_t base = (size_t)b * NN;
  uint32_t bits = 0;
  int j0 = w * 32;
  int jend = min(j0 + 32, nv);
  int jstart = max(j0, i + 1);
  if (i < nv && jstart < jend) {
    float4 bi = sxyxy[base + i];
    float ai = sarea[base + i];
    int ci = scls[base + i];
    for (int j = jstart; j < jend; ++j) {
      float4 bj = sxyxy[base + j];
      float xx1 = fmaxf(bi.x, bj.x);
      float yy1 = fmaxf(bi.y, bj.y);
      float xx2 = fminf(bi.z, bj.z);
      float yy2 = fminf(bi.w, bj.w);
      float cw = fmaxf(xx2 - xx1 + 1.0f, 0.0f);
      float ch = fmaxf(yy2 - yy1 + 1.0f, 0.0f);
      float inter = __fmul_rn(cw, ch);               // block fp-contract
      float aj = sarea[base + j];
      float denom = (ai + aj) - inter;               // same assoc as reference
      float iou = inter / denom;
      if (iou >= NMS_THRV && scls[base + j] == ci) bits |= (1u << (j - j0));
    }
  }
  masksT[((size_t)b * 64 + w) * NN + i] = bits;
}

// ============ K3: scan (wave 0) + head output write (all waves) ============
// Det data for each thread's rows is preloaded into registers BEFORE the
// barrier (independent of the scan) so the gather latency hides behind wave
// 0's scan. Tail rows (r >= nv) were written by k_rank_all. Static
// compile-time-indexed register arrays only (round-3 lesson).
__global__ __launch_bounds__(512) void k_scan_write(
    const uint32_t* __restrict__ masksT,
    const int* __restrict__ nvalid,
    const float4* __restrict__ sxyxy,
    const float* __restrict__ sobj,
    const float* __restrict__ sconf,
    const int* __restrict__ scls,
    float* __restrict__ out) {
  __shared__ uint32_t rsh[64];
  int b = blockIdx.x;
  int t = threadIdx.x;
  int nv = nvalid[b];
  size_t base = (size_t)b * NN;

  // ---- preload det data (scan-independent; hides behind the scan) ----
  float4 pxy[4];
  float po[4], pcf[4];
  int pcl[4];
  #pragma unroll
  for (int rep = 0; rep < 4; ++rep) {
    int r = t + rep * 512;
    bool in = r < nv;
    size_t idx = base + r;
    pxy[rep] = in ? sxyxy[idx] : make_float4(0.f, 0.f, 0.f, 0.f);
    po[rep] = in ? sobj[idx] : 0.f;
    pcf[rep] = in ? sconf[idx] : 0.f;
    pcl[rep] = in ? scls[idx] : 0;
  }

  if (t < 64) {
    int lane = t;
    int nwords = (nv + 31) >> 5;
    int nch4 = (nwords + 3) & ~3;       // chunks, rounded to pipeline depth
    bool act = lane < nwords;
    const uint4* col = (const uint4*)(masksT + ((size_t)b * 64 + lane) * NN);
    uint32_t remv = 0;
    uint4 z4; z4.x = z4.y = z4.z = z4.w = 0u;
    uint4 A[8], B[8], C[8], D[8];
    #pragma unroll
    for (int q = 0; q < 8; ++q) { A[q] = z4; B[q] = z4; C[q] = z4; D[q] = z4; }
#define LOADBUF(BUF, CH) do {                                          \
      if (act) {                                                       \
        int rr = (CH) < 64 ? (CH) : 0;                                 \
        _Pragma("unroll")                                              \
        for (int q = 0; q < 8; ++q) BUF[q] = col[rr * 8 + q];          \
      }                                                                \
    } while (0)
    LOADBUF(A, 0); LOADBUF(B, 1); LOADBUF(C, 2); LOADBUF(D, 3);
#define STEP(BUF, CH, RCH) do {                                        \
      uint32_t cur[32];                                                \
      _Pragma("unroll")                                                \
      for (int q = 0; q < 8; ++q) {                                    \
        cur[4*q+0] = BUF[q].x; cur[4*q+1] = BUF[q].y;                  \
        cur[4*q+2] = BUF[q].z; cur[4*q+3] = BUF[q].w;                  \
      }                                                                \
      LOADBUF(BUF, RCH);                                               \
      uint32_t all_or = 0;                                             \
      _Pragma("unroll")                                                \
      for (int d = 0; d < 32; ++d) all_or |= cur[d];                   \
      uint32_t word_c = (uint32_t)__shfl((int)remv, (CH), 64);         \
      uint32_t diag   = (uint32_t)__shfl((int)all_or, (CH), 64);       \
      if (diag == 0u) {                                                \
        if (word_c == 0u) {                                            \
          remv |= all_or;                                              \
        } else {                                                       \
          uint32_t acc = 0;                                            \
          _Pragma("unroll")                                            \
          for (int d = 0; d < 32; ++d)                                 \
            acc |= ((word_c >> d) & 1u) ? 0u : cur[d];                 \
          remv |= acc;                                                 \
        }                                                              \
      } else {                                                         \
        uint32_t wc = word_c, acc = 0;                                 \
        _Pragma("unroll")                                              \
        for (int d = 0; d < 32; ++d) {                                 \
          uint32_t dd = (uint32_t)__shfl((int)cur[d], (CH), 64);       \
          if (((wc >> d) & 1u) == 0u) { wc |= dd; acc |= cur[d]; }     \
        }                                                              \
        remv |= acc;                                                   \
      }                                                                \
    } while (0)
    for (int c = 0; c < nch4; c += 4) {
      STEP(A, c + 0, c + 4);
      STEP(B, c + 1, c + 5);
      STEP(C, c + 2, c + 6);
      STEP(D, c + 3, c + 7);
    }
#undef STEP
#undef LOADBUF
    rsh[lane] = remv;
  }
  __syncthreads();

  // ---- head rows only (r < nv); tail handled by k_rank_all ----
  #pragma unroll
  for (int rep = 0; rep < 4; ++rep) {
    int r = t + rep * 512;
    if (r >= nv) break;
    uint32_t wrd = rsh[r >> 5];
    bool keep = !((wrd >> (r & 31)) & 1u);
    float4 xy = keep ? pxy[rep] : make_float4(0.f, 0.f, 0.f, 0.f);
    float o = keep ? po[rep] : 0.f;
    float cf = keep ? pcf[rep] : 0.f;
    float cl = keep ? (float)pcl[rep] : 0.f;
    float4* op = (float4*)(out + (base + r) * 8);
    op[0] = make_float4((float)b, xy.x, xy.y, xy.z);
    op[1] = make_float4(xy.w, o, cf, cl);
  }
}

extern "C" void kernel_launch(void* const* d_in, const int* in_sizes, int n_in,
                              void* d_out, int out_size, void* d_ws, size_t ws_size,
                              hipStream_t stream) {
  const float4* boxes = (const float4*)d_in[0];        // [B][N][4]
  const float* obj = (const float*)d_in[1];            // [B][N]
  const float* logits = (const float*)d_in[2];         // [B][N][80]
  float* out = (float*)d_out;                          // [B][N][8]

  char* ws = (char*)d_ws;
  size_t off = 0;
  float4* sxyxy = (float4*)(ws + off);            off += (size_t)BB * NN * 16;
  float* sarea = (float*)(ws + off);              off += (size_t)BB * NN * 4;
  float* sobj = (float*)(ws + off);               off += (size_t)BB * NN * 4;
  float* sconf = (float*)(ws + off);              off += (size_t)BB * NN * 4;
  int* scls = (int*)(ws + off);                   off += (size_t)BB * NN * 4;
  int* nvalid = (int*)(ws + off);                 off += 256;
  uint32_t* masksT = (uint32_t*)(ws + off);       off += (size_t)BB * NN * 64 * 4;

  hipLaunchKernelGGL(k_rank_all, dim3(NN / 256, BB), dim3(256), 0, stream,
                     boxes, obj, logits,
                     sxyxy, sarea, sobj, sconf, scls, nvalid, out);
  hipLaunchKernelGGL(k_masks, dim3(NN * 64 / 256, BB), dim3(256), 0, stream,
                     sxyxy, sarea, scls, nvalid, masksT);
  hipLaunchKernelGGL(k_scan_write, dim3(BB), dim3(512), 0, stream,
                     masksT, nvalid, sxyxy, sobj, sconf, scls, out);
}